// Round 3
// baseline (596.488 us; speedup 1.0000x reference)
//
#include <hip/hip_runtime.h>

// N=4, C=64 (per input), C2=128, H=W=256, HW=65536
// y (dwconv output) staged in d_out (4*128*65536 floats = out_size exactly);
// K2 fully drains y->flow before K3 overwrites d_out.
// ws layout (floats): stats[1024] | flow[4*262144] | part[2*8192]

__device__ __forceinline__ float gelu_exact(float x) {
    return 0.5f * x * (1.0f + erff(x * 0.7071067811865475f));
}

// ---------------- K1: depthwise 5x5 conv + bias + per-tile partial stats ----------------
// grid = 8192 (512 planes * 16 tiles), XCD-swizzled so consecutive tiles of a
// plane run on the same XCD (halo rows become L2 hits). block = 256.
__global__ __launch_bounds__(256) void k_dwconv(
    const float* __restrict__ x1, const float* __restrict__ x2,
    const float* __restrict__ dww, const float* __restrict__ dwb,
    float* __restrict__ y, float* __restrict__ part)
{
    // XCD swizzle: 8192 blocks, 8 XCDs -> each XCD gets 1024 consecutive work ids
    const int wid   = ((blockIdx.x & 7) << 10) + (blockIdx.x >> 3);
    const int plane = wid >> 4;          // n*128 + c2
    const int tile  = wid & 15;
    const int n     = plane >> 7;
    const int c2    = plane & 127;
    const int t     = threadIdx.x;
    const int R0    = tile << 4;         // first output row of this tile

    const float* src = (c2 < 64)
        ? x1 + ((size_t)(n * 64 + c2) << 16)
        : x2 + ((size_t)(n * 64 + (c2 - 64)) << 16);

    float wv[25];
#pragma unroll
    for (int i = 0; i < 25; ++i) wv[i] = dww[c2 * 25 + i];
    const float bias = dwb[c2];

    // 20 input rows (16 + 2 halo each side), col c stored at [c+2]
    __shared__ __align__(16) float rows[20][264];

    if (t < 80) {                        // zero the 4 halo columns of all 20 rows
        const int r = t >> 2, k = t & 3;
        rows[r][(k < 2) ? k : 256 + k] = 0.0f;
    }
#pragma unroll
    for (int k = 0; k < 5; ++k) {
        const int i  = t + (k << 8);     // 0..1279
        const int r  = i >> 6;           // 0..19
        const int g  = i & 63;           // float4 group in row
        const int gr = R0 - 2 + r;       // global input row
        float4 v = make_float4(0.f, 0.f, 0.f, 0.f);
        if (gr >= 0 && gr < 256) v = *(const float4*)(src + (gr << 8) + (g << 2));
        float2* dst = (float2*)&rows[r][2 + (g << 2)];
        dst[0] = make_float2(v.x, v.y);
        dst[1] = make_float2(v.z, v.w);
    }
    __syncthreads();

    float* yo = y + ((size_t)plane << 16);
    const int q  = t & 63;               // column group: cols 4q..4q+3
    const int rr = t >> 6;               // row within 4-row group
    float s1 = 0.0f, s2 = 0.0f;

#pragma unroll
    for (int it = 0; it < 4; ++it) {
        const int lr = rr + (it << 2);   // local output row 0..15
        float a0 = bias, a1 = bias, a2 = bias, a3 = bias;
#pragma unroll
        for (int dy = 0; dy < 5; ++dy) {
            const float* R = &rows[lr + dy][q << 2];
            float4 A = *(const float4*)R;
            float4 B = *(const float4*)(R + 4);
            const float w0 = wv[dy*5+0], w1 = wv[dy*5+1], w2 = wv[dy*5+2],
                        w3 = wv[dy*5+3], w4 = wv[dy*5+4];
            a0 = fmaf(w0, A.x, a0); a0 = fmaf(w1, A.y, a0); a0 = fmaf(w2, A.z, a0);
            a0 = fmaf(w3, A.w, a0); a0 = fmaf(w4, B.x, a0);
            a1 = fmaf(w0, A.y, a1); a1 = fmaf(w1, A.z, a1); a1 = fmaf(w2, A.w, a1);
            a1 = fmaf(w3, B.x, a1); a1 = fmaf(w4, B.y, a1);
            a2 = fmaf(w0, A.z, a2); a2 = fmaf(w1, A.w, a2); a2 = fmaf(w2, B.x, a2);
            a2 = fmaf(w3, B.y, a2); a2 = fmaf(w4, B.z, a2);
            a3 = fmaf(w0, A.w, a3); a3 = fmaf(w1, B.x, a3); a3 = fmaf(w2, B.y, a3);
            a3 = fmaf(w3, B.z, a3); a3 = fmaf(w4, B.w, a3);
        }
        *(float4*)(yo + ((R0 + lr) << 8) + (q << 2)) = make_float4(a0, a1, a2, a3);
        s1 += a0 + a1 + a2 + a3;
        s2 = fmaf(a0, a0, s2); s2 = fmaf(a1, a1, s2);
        s2 = fmaf(a2, a2, s2); s2 = fmaf(a3, a3, s2);
    }

#pragma unroll
    for (int off = 32; off > 0; off >>= 1) {
        s1 += __shfl_down(s1, off);
        s2 += __shfl_down(s2, off);
    }
    __shared__ float red[8];
    const int wave = t >> 6;
    if ((t & 63) == 0) { red[wave] = s1; red[4 + wave] = s2; }
    __syncthreads();
    if (t == 0) {
        part[tile * 512 + plane]        = red[0] + red[1] + red[2] + red[3];
        part[8192 + tile * 512 + plane] = red[4] + red[5] + red[6] + red[7];
    }
}

// ---------------- K1b: finalize per-plane mean/rstd ----------------
__global__ __launch_bounds__(256) void k_stats(
    const float* __restrict__ part, float* __restrict__ stats)
{
    const int p = blockIdx.x * 256 + threadIdx.x;   // 0..511
    float a = 0.0f, b = 0.0f;
#pragma unroll
    for (int tl = 0; tl < 16; ++tl) {
        a += part[tl * 512 + p];
        b += part[8192 + tl * 512 + p];
    }
    const float mean = a * (1.0f / 65536.0f);
    const float var  = b * (1.0f / 65536.0f) - mean * mean;
    stats[2 * p]     = mean;
    stats[2 * p + 1] = rsqrtf(var + 1e-5f);
}

// ---------------- K2: instance-norm + GELU + 1x1 conv -> flow ----------------
__global__ __launch_bounds__(256) void k_flow(
    const float* __restrict__ y, const float* __restrict__ stats,
    const float* __restrict__ pww, float* __restrict__ flow)
{
    const int bid = blockIdx.x;            // 256 blocks, 64 per n
    const int n   = bid >> 6;
    const int t   = threadIdx.x;
    const int p4  = ((bid & 63) << 8) | t; // float4 index within n-plane [0,16384)

    __shared__ float sm[128], sr[128], spw[512];
    if (t < 128) {
        sm[t] = stats[(n * 128 + t) * 2];
        sr[t] = stats[(n * 128 + t) * 2 + 1];
    } else {
        const int i = t - 128;
        spw[i]       = pww[i];
        spw[i + 128] = pww[i + 128];
        spw[i + 256] = pww[i + 256];
        spw[i + 384] = pww[i + 384];
    }
    __syncthreads();

    const float4* y4 = (const float4*)y + (((size_t)n * 128) << 14) + p4;
    float4 f0 = make_float4(0,0,0,0), f1 = f0, f2 = f0, f3 = f0;
#pragma unroll 4
    for (int c = 0; c < 128; ++c) {
        float4 v = y4[(size_t)c << 14];
        const float m = sm[c], rs = sr[c];
        const float g0 = gelu_exact((v.x - m) * rs);
        const float g1 = gelu_exact((v.y - m) * rs);
        const float g2 = gelu_exact((v.z - m) * rs);
        const float g3 = gelu_exact((v.w - m) * rs);
        float w;
        w = spw[c];       f0.x = fmaf(w, g0, f0.x); f0.y = fmaf(w, g1, f0.y);
                          f0.z = fmaf(w, g2, f0.z); f0.w = fmaf(w, g3, f0.w);
        w = spw[128 + c]; f1.x = fmaf(w, g0, f1.x); f1.y = fmaf(w, g1, f1.y);
                          f1.z = fmaf(w, g2, f1.z); f1.w = fmaf(w, g3, f1.w);
        w = spw[256 + c]; f2.x = fmaf(w, g0, f2.x); f2.y = fmaf(w, g1, f2.y);
                          f2.z = fmaf(w, g2, f2.z); f2.w = fmaf(w, g3, f2.w);
        w = spw[384 + c]; f3.x = fmaf(w, g0, f3.x); f3.y = fmaf(w, g1, f3.y);
                          f3.z = fmaf(w, g2, f3.z); f3.w = fmaf(w, g3, f3.w);
    }
    float4* F = (float4*)flow;
    const int fi = (n << 14) + p4;
    F[fi]          = f0;
    F[65536 + fi]  = f1;
    F[131072 + fi] = f2;
    F[196608 + fi] = f3;
}

// ---------------- K3: bilinear warp + subtract ----------------
// grid = 1024 (4 n * 4 channel-chunks * 64 row-quads), XCD-swizzled so each XCD
// owns contiguous row ranges (gather halo rows hit L2). 4 pixels/thread
// (float4 direct reads/stores); 16 channels per block.
__global__ __launch_bounds__(256, 4) void k_warp(
    const float* __restrict__ x1, const float* __restrict__ x2,
    const float* __restrict__ flow, float* __restrict__ out)
{
    const int wid   = ((blockIdx.x & 7) << 7) + (blockIdx.x >> 3);  // 0..1023
    const int n     = wid >> 8;
    const int chunk = (wid >> 6) & 3;
    const int rb    = wid & 63;            // 4-row group
    const int t     = threadIdx.x;
    const int p0    = (rb << 10) + (t << 2);   // base pixel (aligned 4, one row)
    const int h     = p0 >> 8;
    const int w0    = p0 & 255;
    const int np0   = (n << 16) + p0;
    const float S   = 255.0f / 512.0f;         // (W-1)/(2W)

    const float4 fxa = *(const float4*)(flow + np0);
    const float4 fya = *(const float4*)(flow + 262144 + np0);
    const float4 fxb = *(const float4*)(flow + 524288 + np0);
    const float4 fyb = *(const float4*)(flow + 786432 + np0);

    int   idxA[4][4], idxB[4][4];
    float wtA[4][4],  wtB[4][4];

    auto bil = [&](float gx, float gy, int* idx, float* wt) {
        float x0f = floorf(gx), y0f = floorf(gy);
        float wx1 = gx - x0f, wy1 = gy - y0f;
        float wx0 = 1.0f - wx1, wy0 = 1.0f - wy1;
        int ix0 = (int)x0f, iy0 = (int)y0f;
        int ix1 = ix0 + 1,  iy1 = iy0 + 1;
        bool vx0 = (ix0 >= 0) && (ix0 <= 255), vx1 = (ix1 >= 0) && (ix1 <= 255);
        bool vy0 = (iy0 >= 0) && (iy0 <= 255), vy1 = (iy1 >= 0) && (iy1 <= 255);
        int x0c = min(max(ix0, 0), 255), x1c = min(max(ix1, 0), 255);
        int y0c = min(max(iy0, 0), 255), y1c = min(max(iy1, 0), 255);
        idx[0] = (y0c << 8) | x0c; idx[1] = (y0c << 8) | x1c;
        idx[2] = (y1c << 8) | x0c; idx[3] = (y1c << 8) | x1c;
        wt[0] = wx0 * wy0 * ((vx0 && vy0) ? 1.0f : 0.0f);
        wt[1] = wx1 * wy0 * ((vx1 && vy0) ? 1.0f : 0.0f);
        wt[2] = wx0 * wy1 * ((vx0 && vy1) ? 1.0f : 0.0f);
        wt[3] = wx1 * wy1 * ((vx1 && vy1) ? 1.0f : 0.0f);
    };

    {
        const float fx[4] = {fxa.x, fxa.y, fxa.z, fxa.w};
        const float fy[4] = {fya.x, fya.y, fya.z, fya.w};
#pragma unroll
        for (int j = 0; j < 4; ++j)
            bil((float)(w0 + j) + fx[j] * S, (float)h + fy[j] * S, idxA[j], wtA[j]);
    }
    {
        const float fx[4] = {fxb.x, fxb.y, fxb.z, fxb.w};
        const float fy[4] = {fyb.x, fyb.y, fyb.z, fyb.w};
#pragma unroll
        for (int j = 0; j < 4; ++j)
            bil((float)(w0 + j) + fx[j] * S, (float)h + fy[j] * S, idxB[j], wtB[j]);
    }

    const int c0 = chunk << 4;
    const float* P1 = x1 + ((size_t)(n * 64 + c0) << 16);
    const float* P2 = x2 + ((size_t)(n * 64 + c0) << 16);
    float* O1 = out + ((size_t)(n * 64 + c0) << 16) + p0;
    float* O2 = out + 16777216 + ((size_t)(n * 64 + c0) << 16) + p0;

#pragma unroll 2
    for (int c = 0; c < 16; ++c) {
        const size_t base = (size_t)c << 16;
        const float* q1 = P1 + base;
        const float* q2 = P2 + base;
        float4 d1 = *(const float4*)(q1 + p0);
        float4 d2 = *(const float4*)(q2 + p0);
        float4 o1, o2;
        o1.x = wtA[0][0]*q1[idxA[0][0]] + wtA[0][1]*q1[idxA[0][1]]
             + wtA[0][2]*q1[idxA[0][2]] + wtA[0][3]*q1[idxA[0][3]] - d2.x;
        o1.y = wtA[1][0]*q1[idxA[1][0]] + wtA[1][1]*q1[idxA[1][1]]
             + wtA[1][2]*q1[idxA[1][2]] + wtA[1][3]*q1[idxA[1][3]] - d2.y;
        o1.z = wtA[2][0]*q1[idxA[2][0]] + wtA[2][1]*q1[idxA[2][1]]
             + wtA[2][2]*q1[idxA[2][2]] + wtA[2][3]*q1[idxA[2][3]] - d2.z;
        o1.w = wtA[3][0]*q1[idxA[3][0]] + wtA[3][1]*q1[idxA[3][1]]
             + wtA[3][2]*q1[idxA[3][2]] + wtA[3][3]*q1[idxA[3][3]] - d2.w;
        o2.x = wtB[0][0]*q2[idxB[0][0]] + wtB[0][1]*q2[idxB[0][1]]
             + wtB[0][2]*q2[idxB[0][2]] + wtB[0][3]*q2[idxB[0][3]] - d1.x;
        o2.y = wtB[1][0]*q2[idxB[1][0]] + wtB[1][1]*q2[idxB[1][1]]
             + wtB[1][2]*q2[idxB[1][2]] + wtB[1][3]*q2[idxB[1][3]] - d1.y;
        o2.z = wtB[2][0]*q2[idxB[2][0]] + wtB[2][1]*q2[idxB[2][1]]
             + wtB[2][2]*q2[idxB[2][2]] + wtB[2][3]*q2[idxB[2][3]] - d1.z;
        o2.w = wtB[3][0]*q2[idxB[3][0]] + wtB[3][1]*q2[idxB[3][1]]
             + wtB[3][2]*q2[idxB[3][2]] + wtB[3][3]*q2[idxB[3][3]] - d1.w;
        *(float4*)(O1 + base) = o1;
        *(float4*)(O2 + base) = o2;
    }
}

extern "C" void kernel_launch(void* const* d_in, const int* in_sizes, int n_in,
                              void* d_out, int out_size, void* d_ws, size_t ws_size,
                              hipStream_t stream) {
    const float* x1  = (const float*)d_in[0];
    const float* x2  = (const float*)d_in[1];
    const float* dww = (const float*)d_in[2];
    const float* dwb = (const float*)d_in[3];
    const float* pww = (const float*)d_in[4];
    float* out = (float*)d_out;

    float* wsf   = (float*)d_ws;
    float* stats = wsf;                       // 1024 floats
    float* flow  = wsf + 1024;                // 4*262144 floats
    float* part  = wsf + 1024 + 1048576;      // 2*8192 floats
    float* y     = out;                       // stage dwconv output in d_out

    k_dwconv<<<8192, 256, 0, stream>>>(x1, x2, dww, dwb, y, part);
    k_stats<<<2, 256, 0, stream>>>(part, stats);
    k_flow<<<256, 256, 0, stream>>>(y, stats, pww, flow);
    k_warp<<<1024, 256, 0, stream>>>(x1, x2, flow, out);
}

// Round 4
// 384.799 us; speedup vs baseline: 1.5501x; 1.5501x over previous
//
#include <hip/hip_runtime.h>

// N=4, C=64 (per input), C2=128, H=W=256, HW=65536
// y (dwconv output) staged in d_out (4*128*65536 floats = out_size exactly);
// K2 fully drains y->flow before K3 overwrites d_out.
// ws layout (floats): stats[1024] | flow[4*262144] | part[2*8192]

__device__ __forceinline__ float gelu_exact(float x) {
    return 0.5f * x * (1.0f + erff(x * 0.7071067811865475f));
}

// ---------------- K1: depthwise 5x5 conv + bias + per-tile partial stats ----------------
// grid = 8192 (512 planes * 16 tiles), XCD-swizzled so consecutive tiles of a
// plane run on the same XCD (halo rows become L2 hits). block = 256.
__global__ __launch_bounds__(256) void k_dwconv(
    const float* __restrict__ x1, const float* __restrict__ x2,
    const float* __restrict__ dww, const float* __restrict__ dwb,
    float* __restrict__ y, float* __restrict__ part)
{
    const int wid   = ((blockIdx.x & 7) << 10) + (blockIdx.x >> 3);
    const int plane = wid >> 4;          // n*128 + c2
    const int tile  = wid & 15;
    const int n     = plane >> 7;
    const int c2    = plane & 127;
    const int t     = threadIdx.x;
    const int R0    = tile << 4;         // first output row of this tile

    const float* src = (c2 < 64)
        ? x1 + ((size_t)(n * 64 + c2) << 16)
        : x2 + ((size_t)(n * 64 + (c2 - 64)) << 16);

    float wv[25];
#pragma unroll
    for (int i = 0; i < 25; ++i) wv[i] = dww[c2 * 25 + i];
    const float bias = dwb[c2];

    __shared__ __align__(16) float rows[20][264];

    if (t < 80) {                        // zero the 4 halo columns of all 20 rows
        const int r = t >> 2, k = t & 3;
        rows[r][(k < 2) ? k : 256 + k] = 0.0f;
    }
#pragma unroll
    for (int k = 0; k < 5; ++k) {
        const int i  = t + (k << 8);     // 0..1279
        const int r  = i >> 6;           // 0..19
        const int g  = i & 63;           // float4 group in row
        const int gr = R0 - 2 + r;       // global input row
        float4 v = make_float4(0.f, 0.f, 0.f, 0.f);
        if (gr >= 0 && gr < 256) v = *(const float4*)(src + (gr << 8) + (g << 2));
        float2* dst = (float2*)&rows[r][2 + (g << 2)];
        dst[0] = make_float2(v.x, v.y);
        dst[1] = make_float2(v.z, v.w);
    }
    __syncthreads();

    float* yo = y + ((size_t)plane << 16);
    const int q  = t & 63;
    const int rr = t >> 6;
    float s1 = 0.0f, s2 = 0.0f;

#pragma unroll
    for (int it = 0; it < 4; ++it) {
        const int lr = rr + (it << 2);
        float a0 = bias, a1 = bias, a2 = bias, a3 = bias;
#pragma unroll
        for (int dy = 0; dy < 5; ++dy) {
            const float* R = &rows[lr + dy][q << 2];
            float4 A = *(const float4*)R;
            float4 B = *(const float4*)(R + 4);
            const float w0 = wv[dy*5+0], w1 = wv[dy*5+1], w2 = wv[dy*5+2],
                        w3 = wv[dy*5+3], w4 = wv[dy*5+4];
            a0 = fmaf(w0, A.x, a0); a0 = fmaf(w1, A.y, a0); a0 = fmaf(w2, A.z, a0);
            a0 = fmaf(w3, A.w, a0); a0 = fmaf(w4, B.x, a0);
            a1 = fmaf(w0, A.y, a1); a1 = fmaf(w1, A.z, a1); a1 = fmaf(w2, A.w, a1);
            a1 = fmaf(w3, B.x, a1); a1 = fmaf(w4, B.y, a1);
            a2 = fmaf(w0, A.z, a2); a2 = fmaf(w1, A.w, a2); a2 = fmaf(w2, B.x, a2);
            a2 = fmaf(w3, B.y, a2); a2 = fmaf(w4, B.z, a2);
            a3 = fmaf(w0, A.w, a3); a3 = fmaf(w1, B.x, a3); a3 = fmaf(w2, B.y, a3);
            a3 = fmaf(w3, B.z, a3); a3 = fmaf(w4, B.w, a3);
        }
        *(float4*)(yo + ((R0 + lr) << 8) + (q << 2)) = make_float4(a0, a1, a2, a3);
        s1 += a0 + a1 + a2 + a3;
        s2 = fmaf(a0, a0, s2); s2 = fmaf(a1, a1, s2);
        s2 = fmaf(a2, a2, s2); s2 = fmaf(a3, a3, s2);
    }

#pragma unroll
    for (int off = 32; off > 0; off >>= 1) {
        s1 += __shfl_down(s1, off);
        s2 += __shfl_down(s2, off);
    }
    __shared__ float red[8];
    const int wave = t >> 6;
    if ((t & 63) == 0) { red[wave] = s1; red[4 + wave] = s2; }
    __syncthreads();
    if (t == 0) {
        part[tile * 512 + plane]        = red[0] + red[1] + red[2] + red[3];
        part[8192 + tile * 512 + plane] = red[4] + red[5] + red[6] + red[7];
    }
}

// ---------------- K1b: finalize per-plane mean/rstd ----------------
__global__ __launch_bounds__(256) void k_stats(
    const float* __restrict__ part, float* __restrict__ stats)
{
    const int p = blockIdx.x * 256 + threadIdx.x;   // 0..511
    float a = 0.0f, b = 0.0f;
#pragma unroll
    for (int tl = 0; tl < 16; ++tl) {
        a += part[tl * 512 + p];
        b += part[8192 + tl * 512 + p];
    }
    const float mean = a * (1.0f / 65536.0f);
    const float var  = b * (1.0f / 65536.0f) - mean * mean;
    stats[2 * p]     = mean;
    stats[2 * p + 1] = rsqrtf(var + 1e-5f);
}

// ---------------- K2: instance-norm + GELU + 1x1 conv -> flow ----------------
// grid = 1024 (4 blocks/CU). Block covers 64 float4-pixels; each of the 4 waves
// sums a 32-channel quarter; LDS reduce; 64 threads store. 16 waves/CU hides
// the 64KB-stride load latency that made the old 256-block version 1 block/CU.
__global__ __launch_bounds__(256) void k_flow(
    const float* __restrict__ y, const float* __restrict__ stats,
    const float* __restrict__ pww, float* __restrict__ flow)
{
    const int bid = blockIdx.x;
    const int n   = bid >> 8;              // 256 blocks per n
    const int t   = threadIdx.x;
    const int pix = t & 63;
    const int cg  = t >> 6;                // channel group 0..3
    const int p4  = ((bid & 255) << 6) | pix;   // float4 idx within n-plane

    __shared__ float sm[128], sr[128], spw[512];
    __shared__ __align__(16) float4 acc[64][17];

    if (t < 128) {
        sm[t] = stats[(n * 128 + t) * 2];
        sr[t] = stats[(n * 128 + t) * 2 + 1];
    } else {
        const int i = t - 128;
        spw[i]       = pww[i];
        spw[i + 128] = pww[i + 128];
        spw[i + 256] = pww[i + 256];
        spw[i + 384] = pww[i + 384];
    }
    __syncthreads();

    const int cbase = cg << 5;
    const float4* y4 = (const float4*)y + (((size_t)(n * 128 + cbase)) << 14) + p4;
    float4 f0 = make_float4(0,0,0,0), f1 = f0, f2 = f0, f3 = f0;
#pragma unroll 4
    for (int c = 0; c < 32; ++c) {
        float4 v = y4[(size_t)c << 14];
        const int cc = cbase + c;
        const float m = sm[cc], rs = sr[cc];
        const float g0 = gelu_exact((v.x - m) * rs);
        const float g1 = gelu_exact((v.y - m) * rs);
        const float g2 = gelu_exact((v.z - m) * rs);
        const float g3 = gelu_exact((v.w - m) * rs);
        float w;
        w = spw[cc];       f0.x = fmaf(w, g0, f0.x); f0.y = fmaf(w, g1, f0.y);
                           f0.z = fmaf(w, g2, f0.z); f0.w = fmaf(w, g3, f0.w);
        w = spw[128 + cc]; f1.x = fmaf(w, g0, f1.x); f1.y = fmaf(w, g1, f1.y);
                           f1.z = fmaf(w, g2, f1.z); f1.w = fmaf(w, g3, f1.w);
        w = spw[256 + cc]; f2.x = fmaf(w, g0, f2.x); f2.y = fmaf(w, g1, f2.y);
                           f2.z = fmaf(w, g2, f2.z); f2.w = fmaf(w, g3, f2.w);
        w = spw[384 + cc]; f3.x = fmaf(w, g0, f3.x); f3.y = fmaf(w, g1, f3.y);
                           f3.z = fmaf(w, g2, f3.z); f3.w = fmaf(w, g3, f3.w);
    }
    acc[pix][(cg << 2) + 0] = f0;
    acc[pix][(cg << 2) + 1] = f1;
    acc[pix][(cg << 2) + 2] = f2;
    acc[pix][(cg << 2) + 3] = f3;
    __syncthreads();

    if (t < 64) {
        const int fi = (n << 14) + ((bid & 255) << 6) + t;
        float4* F = (float4*)flow;
#pragma unroll
        for (int j = 0; j < 4; ++j) {
            float4 a = acc[t][j];
            float4 b = acc[t][4 + j];
            float4 c = acc[t][8 + j];
            float4 d = acc[t][12 + j];
            float4 s = make_float4(a.x + b.x + c.x + d.x,
                                   a.y + b.y + c.y + d.y,
                                   a.z + b.z + c.z + d.z,
                                   a.w + b.w + c.w + d.w);
            F[j * 65536 + fi] = s;
        }
    }
}

// ---------------- K3: bilinear warp + subtract ----------------
// R2 structure (grid 4096, 1 pixel/thread, 16 channels) + bijective XCD swizzle
// so each XCD owns contiguous rows of the same planes (halo gathers hit L2).
__global__ __launch_bounds__(256) void k_warp(
    const float* __restrict__ x1, const float* __restrict__ x2,
    const float* __restrict__ flow, float* __restrict__ out)
{
    const int wid   = ((blockIdx.x & 7) << 9) + (blockIdx.x >> 3);  // 0..4095
    const int n     = wid >> 10;
    const int chunk = (wid >> 8) & 3;
    const int t     = threadIdx.x;
    const int p     = ((wid & 255) << 8) | t;
    const int h     = p >> 8, w = p & 255;
    const int np    = (n << 16) | p;

    const float fx1 = flow[np];
    const float fy1 = flow[262144 + np];
    const float fx2 = flow[524288 + np];
    const float fy2 = flow[786432 + np];
    const float S = 255.0f / 512.0f;       // (W-1)/(2W)

    float gxa = (float)w + fx1 * S, gya = (float)h + fy1 * S;
    float gxb = (float)w + fx2 * S, gyb = (float)h + fy2 * S;

    int a00, a01, a10, a11, b00, b01, b10, b11;
    float wa00, wa01, wa10, wa11, wb00, wb01, wb10, wb11;
    {
        float x0f = floorf(gxa), y0f = floorf(gya);
        float wx1 = gxa - x0f, wy1 = gya - y0f;
        float wx0 = 1.0f - wx1, wy0 = 1.0f - wy1;
        int ix0 = (int)x0f, iy0 = (int)y0f;
        int ix1 = ix0 + 1,  iy1 = iy0 + 1;
        bool vx0 = (ix0 >= 0) && (ix0 <= 255), vx1 = (ix1 >= 0) && (ix1 <= 255);
        bool vy0 = (iy0 >= 0) && (iy0 <= 255), vy1 = (iy1 >= 0) && (iy1 <= 255);
        int x0c = min(max(ix0, 0), 255), x1c = min(max(ix1, 0), 255);
        int y0c = min(max(iy0, 0), 255), y1c = min(max(iy1, 0), 255);
        a00 = (y0c << 8) | x0c; a01 = (y0c << 8) | x1c;
        a10 = (y1c << 8) | x0c; a11 = (y1c << 8) | x1c;
        wa00 = wx0 * wy0 * ((vx0 && vy0) ? 1.0f : 0.0f);
        wa01 = wx1 * wy0 * ((vx1 && vy0) ? 1.0f : 0.0f);
        wa10 = wx0 * wy1 * ((vx0 && vy1) ? 1.0f : 0.0f);
        wa11 = wx1 * wy1 * ((vx1 && vy1) ? 1.0f : 0.0f);
    }
    {
        float x0f = floorf(gxb), y0f = floorf(gyb);
        float wx1 = gxb - x0f, wy1 = gyb - y0f;
        float wx0 = 1.0f - wx1, wy0 = 1.0f - wy1;
        int ix0 = (int)x0f, iy0 = (int)y0f;
        int ix1 = ix0 + 1,  iy1 = iy0 + 1;
        bool vx0 = (ix0 >= 0) && (ix0 <= 255), vx1 = (ix1 >= 0) && (ix1 <= 255);
        bool vy0 = (iy0 >= 0) && (iy0 <= 255), vy1 = (iy1 >= 0) && (iy1 <= 255);
        int x0c = min(max(ix0, 0), 255), x1c = min(max(ix1, 0), 255);
        int y0c = min(max(iy0, 0), 255), y1c = min(max(iy1, 0), 255);
        b00 = (y0c << 8) | x0c; b01 = (y0c << 8) | x1c;
        b10 = (y1c << 8) | x0c; b11 = (y1c << 8) | x1c;
        wb00 = wx0 * wy0 * ((vx0 && vy0) ? 1.0f : 0.0f);
        wb01 = wx1 * wy0 * ((vx1 && vy0) ? 1.0f : 0.0f);
        wb10 = wx0 * wy1 * ((vx0 && vy1) ? 1.0f : 0.0f);
        wb11 = wx1 * wy1 * ((vx1 && vy1) ? 1.0f : 0.0f);
    }

    const int c0 = chunk << 4;
    const float* P1 = x1 + ((size_t)(n * 64 + c0) << 16);
    const float* P2 = x2 + ((size_t)(n * 64 + c0) << 16);
    float* O1 = out + ((size_t)(n * 64 + c0) << 16) + p;
    float* O2 = out + 16777216 + ((size_t)(n * 64 + c0) << 16) + p;

#pragma unroll 4
    for (int c = 0; c < 16; ++c) {
        const size_t base = (size_t)c << 16;
        const float* q1 = P1 + base;
        const float* q2 = P2 + base;
        float sA = wa00 * q1[a00] + wa01 * q1[a01] + wa10 * q1[a10] + wa11 * q1[a11];
        float sB = wb00 * q2[b00] + wb01 * q2[b01] + wb10 * q2[b10] + wb11 * q2[b11];
        O1[base] = sA - q2[p];
        O2[base] = sB - q1[p];
    }
}

extern "C" void kernel_launch(void* const* d_in, const int* in_sizes, int n_in,
                              void* d_out, int out_size, void* d_ws, size_t ws_size,
                              hipStream_t stream) {
    const float* x1  = (const float*)d_in[0];
    const float* x2  = (const float*)d_in[1];
    const float* dww = (const float*)d_in[2];
    const float* dwb = (const float*)d_in[3];
    const float* pww = (const float*)d_in[4];
    float* out = (float*)d_out;

    float* wsf   = (float*)d_ws;
    float* stats = wsf;                       // 1024 floats
    float* flow  = wsf + 1024;                // 4*262144 floats
    float* part  = wsf + 1024 + 1048576;      // 2*8192 floats
    float* y     = out;                       // stage dwconv output in d_out

    k_dwconv<<<8192, 256, 0, stream>>>(x1, x2, dww, dwb, y, part);
    k_stats<<<2, 256, 0, stream>>>(part, stats);
    k_flow<<<1024, 256, 0, stream>>>(y, stats, pww, flow);
    k_warp<<<4096, 256, 0, stream>>>(x1, x2, flow, out);
}